// Round 15
// baseline (798.500 us; speedup 1.0000x reference)
//
#include <hip/hip_runtime.h>
#include <hip/hip_fp16.h>
#include <stdint.h>

// PrunedInt4Linear: y = x @ dequant(q, scales)^T + bias
// Round 15: 32x32x16 MFMA (+15% measured rate vs 16x16x32, half the
// instruction count) + fragment-ordered ws layout (ds_read = ring base +
// immediate offset + lane*16B: conflict-free, minimal addressing VALU).
// Structure = r14 verbatim: 128x256 tile, 4 waves, 3-deep ring, 2 blocks/CU.

#define M_DIM 8192
#define N_DIM 11008
#define K_DIM 4096
#define MT_TILES 64            // 8192 / 128
#define NT_TILES 43            // 11008 / 256
#define K_TILES 128            // 4096 / 32
#define ASLAB 4096             // shorts per (mt128, kt) A slab: 128 rows * 32 k
#define BSLAB 8192             // shorts per (nt256, kt) B slab: 256 cols * 32 k
#define RSTRIDE 12288          // LDS ring slot: A 4096 + B 8192 shorts

typedef short short8 __attribute__((ext_vector_type(8)));    // 8 bf16
typedef float floatx16 __attribute__((ext_vector_type(16))); // 32x32 acc

// f32 -> bf16, round-to-nearest-even
__device__ __forceinline__ unsigned short f2bf(float f) {
  union { float f; uint32_t u; } c; c.f = f;
  uint32_t u = c.u;
  return (unsigned short)((u + 0x7FFFu + ((u >> 16) & 1u)) >> 16);
}

__device__ __forceinline__ float load_sc(const void* p, size_t idx, bool is_f32) {
  if (is_f32) return ((const float*)p)[idx];
  return __half2float(((const __half*)p)[idx]);
}

// ---- dtype sniffs (verified rounds 2-14) ----
__device__ __forceinline__ bool sniff_q_is_i32(const void* qv) {
  const int* w = (const int*)qv;
  bool ok = true;
  #pragma unroll
  for (int j = 0; j < 16; ++j) {
    int v = w[j];
    ok = ok && (v == (int)(signed char)(v & 0xFF));
  }
  return ok;
}
__device__ __forceinline__ bool sniff_s_is_f32(const void* sv) {
  const float* f = (const float*)sv;
  bool ok = true;
  #pragma unroll
  for (int j = 0; j < 8; ++j) {
    float v = f[j];
    ok = ok && (v > 4e-4f) && (v < 6e-2f);
  }
  return ok;
}

// async global -> LDS, 16B per lane (dest = wave-uniform base + lane*16)
__device__ __forceinline__ void gload_lds16(const short* g, short* l) {
  __builtin_amdgcn_global_load_lds(
      (const __attribute__((address_space(1))) uint32_t*)g,
      (__attribute__((address_space(3))) uint32_t*)l, 16, 0, 0);
}

// ============ fused prep: fragment-ordered ws ============
// B (wq): [nt 43][kt 128][BSLAB]; element (col c, klocal):
//   (c>>5)*1024 + (klocal>>4)*512 + ((c&31) + 32*((klocal>>3)&1))*8 + (klocal&7)
// A (xh): [mt128 64][kt 128][ASLAB]; element (row r, klocal):
//   (r>>5)*1024 + (klocal>>4)*512 + ((r&31) + 32*((klocal>>3)&1))*8 + (klocal&7)
// -> a 32x32x16 fragment = 64 lanes * 16B contiguous (lane-linear, 0-conflict)
__global__ __launch_bounds__(256)
void prep_fused(const float* __restrict__ x, const void* __restrict__ qv,
                const void* __restrict__ sv,
                short* __restrict__ xh, short* __restrict__ wq) {
  const int tid = threadIdx.x;
  int b = blockIdx.x;

  if (b < NT_TILES * 256) {
    // ---- W dequant ----
    const bool q_is_i32 = sniff_q_is_i32(qv);
    const bool s_is_f32 = sniff_s_is_f32(sv);
    const int nt = b >> 8;
    const int rem = b & 255;
    const int kt = rem >> 1, half = rem & 1;
    const int r = half * 128 + (tid >> 1);     // col within 256-tile
    const int s0 = (tid & 1) * 2;              // 8-k slot base (0 or 2)
    const int o = nt * 256 + r;
    const int k0 = kt * 32 + s0 * 8;

    const float s = load_sc(sv, (size_t)o * 64 + (kt >> 1), s_is_f32);

    int codes[16];
    if (q_is_i32) {
      const int* qq = (const int*)qv + (size_t)o * K_DIM + k0;
      #pragma unroll
      for (int j = 0; j < 4; ++j) {
        int4 t = ((const int4*)qq)[j];
        codes[j*4+0]=t.x; codes[j*4+1]=t.y; codes[j*4+2]=t.z; codes[j*4+3]=t.w;
      }
    } else {
      union { int4 v; int8_t c[16]; } u;
      u.v = *(const int4*)((const int8_t*)qv + (size_t)o * K_DIM + k0);
      #pragma unroll
      for (int j = 0; j < 16; ++j) codes[j] = (int)u.c[j];
    }

    short8 h0, h1;
    #pragma unroll
    for (int j = 0; j < 8; ++j) h0[j] = f2bf((float)codes[j] * s);
    #pragma unroll
    for (int j = 0; j < 8; ++j) h1[j] = f2bf((float)codes[8 + j] * s);

    short* slab = wq + ((size_t)nt * K_TILES + kt) * BSLAB;
    const int cb = r >> 5, rl = r & 31;
    // slot s0   -> kh = s0>>1, lane-half 0 ; slot s0+1 -> kh = s0>>1, half 1
    *(short8*)&slab[cb * 1024 + (s0 >> 1) * 512 + rl * 8]        = h0;
    *(short8*)&slab[cb * 1024 + (s0 >> 1) * 512 + (rl + 32) * 8] = h1;
  } else {
    // ---- x convert ----
    b -= NT_TILES * 256;
    const int mtt = b >> 8;
    const int rem = b & 255;
    const int kt = rem >> 1, half = rem & 1;
    const int r256 = half * 128 + (tid >> 1);
    const int s0 = (tid & 1) * 2;
    const int m = mtt * 256 + r256;
    const int mt = m >> 7, r = m & 127;        // 128-row A tiles
    const int k0 = kt * 32 + s0 * 8;

    const float4* p = (const float4*)(x + (size_t)m * K_DIM + k0);
    float4 f0 = p[0], f1 = p[1], f2 = p[2], f3 = p[3];
    short8 h0, h1;
    h0[0]=f2bf(f0.x); h0[1]=f2bf(f0.y); h0[2]=f2bf(f0.z); h0[3]=f2bf(f0.w);
    h0[4]=f2bf(f1.x); h0[5]=f2bf(f1.y); h0[6]=f2bf(f1.z); h0[7]=f2bf(f1.w);
    h1[0]=f2bf(f2.x); h1[1]=f2bf(f2.y); h1[2]=f2bf(f2.z); h1[3]=f2bf(f2.w);
    h1[4]=f2bf(f3.x); h1[5]=f2bf(f3.y); h1[6]=f2bf(f3.z); h1[7]=f2bf(f3.w);

    short* slab = xh + ((size_t)mt * K_TILES + kt) * ASLAB;
    const int rb = r >> 5, rl = r & 31;
    *(short8*)&slab[rb * 1024 + (s0 >> 1) * 512 + rl * 8]        = h0;
    *(short8*)&slab[rb * 1024 + (s0 >> 1) * 512 + (rl + 32) * 8] = h1;
  }
}

// ============ GEMM: 128x256, BK=32, 4 waves, 2 blocks/CU, 32x32x16 ==========
__global__ __launch_bounds__(256, 2)
void gemm4(const short* __restrict__ xh, const short* __restrict__ wq,
           const void* __restrict__ sv, const void* __restrict__ bv,
           float* __restrict__ C) {
  __shared__ __align__(16) short lds[3 * RSTRIDE];   // 72 KiB: 3-deep ring

  const bool s_is_f32 = sniff_s_is_f32(sv);

  const int tid  = threadIdx.x;
  const int lane = tid & 63;
  const int wid  = tid >> 6;                  // 4 waves
  const int wm = wid >> 1, wn = wid & 1;      // 2x2 -> 64x128 out per wave
  const int l31 = lane & 31, l5 = lane >> 5;

  // nt-major XCD dispatch: 2752 = 8 * 344 (bijective)
  const int bid = blockIdx.x;
  const int xcd = bid & 7;
  const int seq = bid >> 3;                   // [0,344)
  const int nt  = seq >> 3;                   // [0,43)
  const int mt  = xcd * 8 + (seq & 7);        // [0,64)

  const short* Aslab = xh + (size_t)mt * (K_TILES * ASLAB);
  const short* Bslab = wq + (size_t)nt * (K_TILES * BSLAB);

  // fragment offsets (shorts): lane-linear 1KB regions, compile-time frag ids
  int aoff[2][2], boff[2][4];                 // [kh][ma] / [kh][nb]
  #pragma unroll
  for (int kh = 0; kh < 2; ++kh) {
    #pragma unroll
    for (int ma = 0; ma < 2; ++ma)
      aoff[kh][ma] = ((wm * 2 + ma) * 2 + kh) * 512 + lane * 8;
    #pragma unroll
    for (int nb = 0; nb < 4; ++nb)
      boff[kh][nb] = ((wn * 4 + nb) * 2 + kh) * 512 + lane * 8;
  }

  floatx16 acc[2][4];                         // 8 x 32x32 blocks = 128 regs
  #pragma unroll
  for (int i = 0; i < 2; ++i)
    #pragma unroll
    for (int j = 0; j < 4; ++j)
      acc[i][j] = (floatx16)(0.f);

  short8 fa[2][2], fb[2][4], ga[2][2], gb[2][4];   // two named frag sets

#define SBAR __builtin_amdgcn_sched_barrier(0)
#define VMCNT(n) do { asm volatile("s_waitcnt vmcnt(" #n ")"); SBAR; } while (0)
#define LGKM0 do { asm volatile("s_waitcnt lgkmcnt(0)"); SBAR; } while (0)
#define BARRIER do { SBAR; __builtin_amdgcn_s_barrier(); SBAR; } while (0)

// stage = 6 loads: A slab 8 KB (2) + B slab 16 KB (4); linear dest
#define STAGE(t) do {                                                   \
    const int s_ = (t) % 3;                                             \
    const short* gA_ = Aslab + (size_t)(t) * ASLAB;                     \
    const short* gB_ = Bslab + (size_t)(t) * BSLAB;                     \
    short* lA_ = lds + s_ * RSTRIDE;                                    \
    short* lB_ = lA_ + ASLAB;                                           \
    gload_lds16(gA_ + tid * 8,        lA_ + tid * 8);                   \
    gload_lds16(gA_ + 2048 + tid * 8, lA_ + 2048 + tid * 8);            \
    gload_lds16(gB_ + tid * 8,        lB_ + tid * 8);                   \
    gload_lds16(gB_ + 2048 + tid * 8, lB_ + 2048 + tid * 8);            \
    gload_lds16(gB_ + 4096 + tid * 8, lB_ + 4096 + tid * 8);            \
    gload_lds16(gB_ + 6144 + tid * 8, lB_ + 6144 + tid * 8);            \
  } while (0)

#define LOADF(da, db, t) do {                                           \
    const short* lA_ = lds + ((t) % 3) * RSTRIDE;                       \
    const short* lB_ = lA_ + ASLAB;                                     \
    _Pragma("unroll")                                                   \
    for (int kh = 0; kh < 2; ++kh) {                                    \
      _Pragma("unroll")                                                 \
      for (int ma = 0; ma < 2; ++ma)                                    \
        da[kh][ma] = *(const short8*)&lA_[aoff[kh][ma]];                \
      _Pragma("unroll")                                                 \
      for (int nb = 0; nb < 4; ++nb)                                    \
        db[kh][nb] = *(const short8*)&lB_[boff[kh][nb]];                \
    }                                                                   \
  } while (0)

#define DOMFMA(sa, sb) do {                                             \
    __builtin_amdgcn_s_setprio(1);                                      \
    _Pragma("unroll")                                                   \
    for (int kh = 0; kh < 2; ++kh)                                      \
      _Pragma("unroll")                                                 \
      for (int ma = 0; ma < 2; ++ma)                                    \
        _Pragma("unroll")                                               \
        for (int nb = 0; nb < 4; ++nb)                                  \
          acc[ma][nb] = __builtin_amdgcn_mfma_f32_32x32x16_bf16(        \
              sa[kh][ma], sb[kh][nb], acc[ma][nb], 0, 0, 0);            \
    __builtin_amdgcn_s_setprio(0);                                      \
  } while (0)

  // prologue: stage 3 tiles (18 loads); retire tile 0; publish; read frags
  STAGE(0); STAGE(1); STAGE(2);
  VMCNT(12);
  BARRIER;
  LOADF(fa, fb, 0);

  // Steady half-iter (r14-proven): VMCNT(6) retire next tile; LGKM0 drain own
  // ds_reads of the slot about to be overwritten; BARRIER publish; STAGE;
  // LOADF(next) overlaps DOMFMA(cur).
  for (int kt = 0; kt < 124; kt += 2) {
    VMCNT(6);
    LGKM0;
    BARRIER;
    STAGE(kt + 3);
    LOADF(ga, gb, kt + 1);
    DOMFMA(fa, fb);            // tile kt
    VMCNT(6);
    LGKM0;
    BARRIER;
    STAGE(kt + 4);
    LOADF(fa, fb, kt + 2);
    DOMFMA(ga, gb);            // tile kt+1
  }

  // tail (r14-proven)
  VMCNT(6);
  LGKM0;
  BARRIER;
  STAGE(127);
  LOADF(ga, gb, 125);
  DOMFMA(fa, fb);              // 124
  VMCNT(6);
  LGKM0;
  BARRIER;
  LOADF(fa, fb, 126);
  DOMFMA(ga, gb);              // 125
  VMCNT(0);
  LGKM0;
  BARRIER;
  LOADF(ga, gb, 127);
  DOMFMA(fa, fb);              // 126
  DOMFMA(ga, gb);              // 127

#undef STAGE
#undef LOADF
#undef DOMFMA
#undef SBAR
#undef VMCNT
#undef LGKM0
#undef BARRIER

  // epilogue: 32x32 C/D layout (m74/m101-verified):
  //   col = lane&31, row = (reg&3) + 8*(reg>>2) + 4*(lane>>5)
  #pragma unroll
  for (int nb = 0; nb < 4; ++nb) {
    const int col = nt * 256 + wn * 128 + nb * 32 + l31;
    const float bvf = load_sc(bv, (size_t)col, s_is_f32);
    #pragma unroll
    for (int ma = 0; ma < 2; ++ma) {
      const int rbase = mt * 128 + wm * 64 + ma * 32 + l5 * 4;
      #pragma unroll
      for (int L = 0; L < 16; ++L) {
        const int row = rbase + (L & 3) + 8 * (L >> 2);
        C[(size_t)row * N_DIM + col] = acc[ma][nb][L] + bvf;
      }
    }
  }
}

// ============ fallback: round-2-verified fully fused kernel ============
__global__ __launch_bounds__(256)
void gemm_fused(const float* __restrict__ x, const void* __restrict__ qv,
                const void* __restrict__ sv, const void* __restrict__ bv,
                float* __restrict__ C) {
  __shared__ __align__(16) short As[128 * 64];
  __shared__ __align__(16) short Bs[128 * 64];
  typedef float floatx4 __attribute__((ext_vector_type(4)));

  const bool q_is_i32 = sniff_q_is_i32(qv);
  const bool s_is_f32 = sniff_s_is_f32(sv);

  const int tid  = threadIdx.x;
  const int lane = tid & 63;
  const int wid  = tid >> 6;
  const int wm = wid >> 1, wn = wid & 1;
  const int lr = lane & 15, lk = lane >> 4;

  const int nwg = gridDim.x;
  const int cpx = nwg >> 3;
  const int bid = blockIdx.x;
  const int swz = (bid & 7) * cpx + (bid >> 3);
  const int per_g = 4 * 86;
  const int g = swz / per_g;
  const int r = swz - g * per_g;
  const int mt = (g << 2) + (r & 3);
  const int nt = r >> 2;

  const int row0 = mt * 128;
  const int col0 = nt * 128;

  floatx4 acc[4][4];
  #pragma unroll
  for (int i = 0; i < 4; ++i)
    #pragma unroll
    for (int j = 0; j < 4; ++j)
      acc[i][j] = (floatx4){0.f, 0.f, 0.f, 0.f};

  for (int kt = 0; kt < K_DIM / 64; ++kt) {
    const int k0 = kt * 64;
    #pragma unroll
    for (int i = 0; i < 4; ++i) {
      const int cid = i * 256 + tid;
      const int arow = cid >> 3, ac = (cid & 7) << 3;
      const float4* p = (const float4*)(x + (size_t)(row0 + arow) * K_DIM + k0 + ac);
      float4 a = p[0], b = p[1];
      short8 h;
      h[0]=f2bf(a.x); h[1]=f2bf(a.y); h[2]=f2bf(a.z); h[3]=f2bf(a.w);
      h[4]=f2bf(b.x); h[5]=f2bf(b.y); h[6]=f2bf(b.z); h[7]=f2bf(b.w);
      *(short8*)&As[arow * 64 + ac] = h;
    }
    #pragma unroll
    for (int i = 0; i < 2; ++i) {
      const int cid = i * 256 + tid;
      const int brow = cid >> 2, bc = (cid & 3) << 4;
      const float s = load_sc(sv, (size_t)(col0 + brow) * 64 + kt, s_is_f32);
      int codes[16];
      if (q_is_i32) {
        const int* qq = (const int*)qv + (size_t)(col0 + brow) * K_DIM + k0 + bc;
        #pragma unroll
        for (int j = 0; j < 4; ++j) {
          int4 t = ((const int4*)qq)[j];
          codes[j*4+0]=t.x; codes[j*4+1]=t.y; codes[j*4+2]=t.z; codes[j*4+3]=t.w;
        }
      } else {
        union { int4 v; int8_t c[16]; } u;
        u.v = *(const int4*)((const int8_t*)qv + (size_t)(col0 + brow) * K_DIM + k0 + bc);
        #pragma unroll
        for (int j = 0; j < 16; ++j) codes[j] = (int)u.c[j];
      }
      short8 h0, h1;
      #pragma unroll
      for (int j = 0; j < 8; ++j) h0[j] = f2bf((float)codes[j] * s);
      #pragma unroll
      for (int j = 0; j < 8; ++j) h1[j] = f2bf((float)codes[8 + j] * s);
      *(short8*)&Bs[brow * 64 + bc]     = h0;
      *(short8*)&Bs[brow * 64 + bc + 8] = h1;
    }
    __syncthreads();
    #pragma unroll
    for (int ks = 0; ks < 2; ++ks) {
      short8 a[4], b[4];
      #pragma unroll
      for (int mi = 0; mi < 4; ++mi)
        a[mi] = *(const short8*)&As[(wm * 64 + mi * 16 + lr) * 64 + ks * 32 + lk * 8];
      #pragma unroll
      for (int ni = 0; ni < 4; ++ni)
        b[ni] = *(const short8*)&Bs[(wn * 64 + ni * 16 + lr) * 64 + ks * 32 + lk * 8];
      #pragma unroll
      for (int mi = 0; mi < 4; ++mi)
        #pragma unroll
        for (int ni = 0; ni < 4; ++ni)
          acc[mi][ni] = __builtin_amdgcn_mfma_f32_16x16x32_bf16(
              a[mi], b[ni], acc[mi][ni], 0, 0, 0);
    }
    __syncthreads();
  }

  #pragma unroll
  for (int ni = 0; ni < 4; ++ni) {
    const int col = col0 + wn * 64 + ni * 16 + lr;
    const float bvf = load_sc(bv, (size_t)col, s_is_f32);
    #pragma unroll
    for (int mi = 0; mi < 4; ++mi) {
      const int rbase = row0 + wm * 64 + mi * 16 + lk * 4;
      #pragma unroll
      for (int rr = 0; rr < 4; ++rr)
        C[(size_t)(rbase + rr) * N_DIM + col] = acc[mi][ni][rr] + bvf;
    }
  }
}

extern "C" void kernel_launch(void* const* d_in, const int* in_sizes, int n_in,
                              void* d_out, int out_size, void* d_ws, size_t ws_size,
                              hipStream_t stream) {
  const float* x  = (const float*)d_in[0];
  const void*  q  = (const void*)d_in[1];
  const void*  sc = (const void*)d_in[2];
  const void*  bs = (const void*)d_in[3];
  float* y = (float*)d_out;
  (void)in_sizes; (void)n_in; (void)out_size;

  const size_t xh_bytes = (size_t)M_DIM * K_DIM * 2;   // 64 MiB
  const size_t wq_bytes = (size_t)N_DIM * K_DIM * 2;   // ~86 MiB

  if (ws_size >= xh_bytes + wq_bytes) {   // confirmed available (r3-r14)
    short* xh = (short*)d_ws;
    short* wq = (short*)((char*)d_ws + xh_bytes);
    prep_fused<<<NT_TILES * 256 + (M_DIM / 256) * 256, dim3(256), 0, stream>>>(
        x, q, sc, xh, wq);
    gemm4<<<MT_TILES * NT_TILES, dim3(256), 0, stream>>>(xh, wq, sc, bs, y);
  } else {
    gemm_fused<<<(M_DIM / 128) * (N_DIM / 128), dim3(256), 0, stream>>>(x, q, sc, bs, y);
  }
}

// Round 16
// 754.381 us; speedup vs baseline: 1.0585x; 1.0585x over previous
//
#include <hip/hip_runtime.h>
#include <hip/hip_fp16.h>
#include <stdint.h>

// PrunedInt4Linear: y = x @ dequant(q, scales)^T + bias
// Round 16: REVERT to r14 verbatim -- the verified best (748 us total;
// GEMM ~650 us = 1.13 PF, MfmaUtil 54%, 0 bank conflicts, 2 blocks/CU).
// r15's 32x32 MFMA + fragment-ordered ws regressed (coarser issue granularity
// kills cross-block overlap; L2 streaming worse). Structure: prep (dequant W
// + convert x -> bf16, packed+swizzled ws) then 128x256-tile GEMM, 4 waves,
// 3-deep LDS ring (72 KiB), counted vmcnt(6), nt-major XCD dispatch.

#define M_DIM 8192
#define N_DIM 11008
#define K_DIM 4096
#define MT_TILES 64            // 8192 / 128  (M-tile 128)
#define NT_TILES 43            // 11008 / 256
#define K_TILES 128            // 4096 / 32
#define SLAB 8192              // shorts per 256-row, 32-k ws slab
#define RSTRIDE 12288          // shorts per LDS ring slot: A 4096 + B 8192

typedef short short8 __attribute__((ext_vector_type(8)));   // 8 bf16
typedef float floatx4 __attribute__((ext_vector_type(4)));

// f32 -> bf16, round-to-nearest-even
__device__ __forceinline__ unsigned short f2bf(float f) {
  union { float f; uint32_t u; } c; c.f = f;
  uint32_t u = c.u;
  return (unsigned short)((u + 0x7FFFu + ((u >> 16) & 1u)) >> 16);
}

__device__ __forceinline__ float load_sc(const void* p, size_t idx, bool is_f32) {
  if (is_f32) return ((const float*)p)[idx];
  return __half2float(((const __half*)p)[idx]);
}

// ---- dtype sniffs (verified rounds 2-15) ----
__device__ __forceinline__ bool sniff_q_is_i32(const void* qv) {
  const int* w = (const int*)qv;
  bool ok = true;
  #pragma unroll
  for (int j = 0; j < 16; ++j) {
    int v = w[j];
    ok = ok && (v == (int)(signed char)(v & 0xFF));
  }
  return ok;
}
__device__ __forceinline__ bool sniff_s_is_f32(const void* sv) {
  const float* f = (const float*)sv;
  bool ok = true;
  #pragma unroll
  for (int j = 0; j < 8; ++j) {
    float v = f[j];
    ok = ok && (v > 4e-4f) && (v < 6e-2f);
  }
  return ok;
}

// async global -> LDS, 16B per lane (dest = wave-uniform base + lane*16)
__device__ __forceinline__ void gload_lds16(const short* g, short* l) {
  __builtin_amdgcn_global_load_lds(
      (const __attribute__((address_space(1))) uint32_t*)g,
      (__attribute__((address_space(3))) uint32_t*)l, 16, 0, 0);
}

// ============ fused prep (r8/r12/r14-verified) ============
// xh: [mt32 256-row][kt 128][slab]; (r,k): r*32 + ((k/8) ^ ((r>>1)&3))*8 + k%8
// wq: [nt 43][kt 128][slab]; same within-slab swizzle
__global__ __launch_bounds__(256)
void prep_fused(const float* __restrict__ x, const void* __restrict__ qv,
                const void* __restrict__ sv,
                short* __restrict__ xh, short* __restrict__ wq) {
  const int tid = threadIdx.x;
  int b = blockIdx.x;

  if (b < NT_TILES * 256) {
    // ---- W dequant ----
    const bool q_is_i32 = sniff_q_is_i32(qv);
    const bool s_is_f32 = sniff_s_is_f32(sv);
    const int nt = b >> 8;
    const int rem = b & 255;
    const int kt = rem >> 1, half = rem & 1;
    const int r = half * 128 + (tid >> 1);
    const int s0 = (tid & 1) * 2;
    const int o = nt * 256 + r;
    const int k0 = kt * 32 + s0 * 8;

    const float s = load_sc(sv, (size_t)o * 64 + (kt >> 1), s_is_f32);

    int codes[16];
    if (q_is_i32) {
      const int* qq = (const int*)qv + (size_t)o * K_DIM + k0;
      #pragma unroll
      for (int j = 0; j < 4; ++j) {
        int4 t = ((const int4*)qq)[j];
        codes[j*4+0]=t.x; codes[j*4+1]=t.y; codes[j*4+2]=t.z; codes[j*4+3]=t.w;
      }
    } else {
      union { int4 v; int8_t c[16]; } u;
      u.v = *(const int4*)((const int8_t*)qv + (size_t)o * K_DIM + k0);
      #pragma unroll
      for (int j = 0; j < 16; ++j) codes[j] = (int)u.c[j];
    }

    short8 h0, h1;
    #pragma unroll
    for (int j = 0; j < 8; ++j) h0[j] = f2bf((float)codes[j] * s);
    #pragma unroll
    for (int j = 0; j < 8; ++j) h1[j] = f2bf((float)codes[8 + j] * s);

    const int w = (r >> 1) & 3;
    short* slab = wq + ((size_t)nt * K_TILES + kt) * SLAB;
    *(short8*)&slab[r * 32 + ((s0    ) ^ w) * 8] = h0;
    *(short8*)&slab[r * 32 + ((s0 + 1) ^ w) * 8] = h1;
  } else {
    // ---- x convert ----
    b -= NT_TILES * 256;
    const int mt = b >> 8;
    const int rem = b & 255;
    const int kt = rem >> 1, half = rem & 1;
    const int r = half * 128 + (tid >> 1);
    const int s0 = (tid & 1) * 2;
    const int k0 = kt * 32 + s0 * 8;

    const float4* p = (const float4*)(x + (size_t)(mt * 256 + r) * K_DIM + k0);
    float4 f0 = p[0], f1 = p[1], f2 = p[2], f3 = p[3];
    short8 h0, h1;
    h0[0]=f2bf(f0.x); h0[1]=f2bf(f0.y); h0[2]=f2bf(f0.z); h0[3]=f2bf(f0.w);
    h0[4]=f2bf(f1.x); h0[5]=f2bf(f1.y); h0[6]=f2bf(f1.z); h0[7]=f2bf(f1.w);
    h1[0]=f2bf(f2.x); h1[1]=f2bf(f2.y); h1[2]=f2bf(f2.z); h1[3]=f2bf(f2.w);
    h1[4]=f2bf(f3.x); h1[5]=f2bf(f3.y); h1[6]=f2bf(f3.z); h1[7]=f2bf(f3.w);

    const int w = (r >> 1) & 3;
    short* slab = xh + ((size_t)mt * K_TILES + kt) * SLAB;
    *(short8*)&slab[r * 32 + ((s0    ) ^ w) * 8] = h0;
    *(short8*)&slab[r * 32 + ((s0 + 1) ^ w) * 8] = h1;
  }
}

// ============ GEMM: 128x256 tile, BK=32, 4 waves, 2 blocks/CU ============
__global__ __launch_bounds__(256, 2)
void gemm4(const short* __restrict__ xh, const short* __restrict__ wq,
           const void* __restrict__ sv, const void* __restrict__ bv,
           float* __restrict__ C) {
  __shared__ __align__(16) short lds[3 * RSTRIDE];   // 72 KiB: 3-deep ring

  const bool s_is_f32 = sniff_s_is_f32(sv);

  const int tid  = threadIdx.x;
  const int lane = tid & 63;
  const int wid  = tid >> 6;                  // 4 waves
  const int wm = wid >> 1, wn = wid & 1;      // 2x2 -> 64x128 out per wave
  const int lr = lane & 15, lk = lane >> 4;

  // nt-major XCD dispatch: 2752 = 8 * 344, 344 = 43 * 8 (bijective)
  const int bid = blockIdx.x;
  const int xcd = bid & 7;
  const int seq = bid >> 3;                   // [0,344)
  const int nt  = seq >> 3;                   // [0,43)
  const int mt  = xcd * 8 + (seq & 7);        // [0,64) (128-row tiles)

  // A = 128-row half of the 256-row ws slab (contiguous; swizzle invariant)
  const short* Aslab = xh + (size_t)(mt >> 1) * (K_TILES * SLAB) + (mt & 1) * 4096;
  const short* Bslab = wq + (size_t)nt * (K_TILES * SLAB);

  // fragment LDS offsets (r4-verified swizzle, 0 conflicts)
  const int swz8 = (lk ^ ((lr >> 1) & 3)) << 3;
  int aoff[4], boff[8];
  #pragma unroll
  for (int mi = 0; mi < 4; ++mi) aoff[mi] = (wm * 64 + mi * 16 + lr) * 32 + swz8;
  #pragma unroll
  for (int ni = 0; ni < 8; ++ni) boff[ni] = (wn * 128 + ni * 16 + lr) * 32 + swz8;

  floatx4 acc[4][8];
  #pragma unroll
  for (int i = 0; i < 4; ++i)
    #pragma unroll
    for (int j = 0; j < 8; ++j)
      acc[i][j] = (floatx4){0.f, 0.f, 0.f, 0.f};

  short8 fa[4], fb[8], ga[4], gb[8];   // two named frag sets (rule #20)

#define SBAR __builtin_amdgcn_sched_barrier(0)
#define VMCNT(n) do { asm volatile("s_waitcnt vmcnt(" #n ")"); SBAR; } while (0)
#define LGKM0 do { asm volatile("s_waitcnt lgkmcnt(0)"); SBAR; } while (0)
#define BARRIER do { SBAR; __builtin_amdgcn_s_barrier(); SBAR; } while (0)

// stage = 6 loads: A half-slab 8 KB (2) + B slab 16 KB (4)
#define STAGE(t) do {                                                   \
    const int s_ = (t) % 3;                                             \
    const short* gA_ = Aslab + (size_t)(t) * SLAB;                      \
    const short* gB_ = Bslab + (size_t)(t) * SLAB;                      \
    short* lA_ = lds + s_ * RSTRIDE;                                    \
    short* lB_ = lA_ + 4096;                                            \
    gload_lds16(gA_ + tid * 8,        lA_ + tid * 8);                   \
    gload_lds16(gA_ + 2048 + tid * 8, lA_ + 2048 + tid * 8);            \
    gload_lds16(gB_ + tid * 8,        lB_ + tid * 8);                   \
    gload_lds16(gB_ + 2048 + tid * 8, lB_ + 2048 + tid * 8);            \
    gload_lds16(gB_ + 4096 + tid * 8, lB_ + 4096 + tid * 8);            \
    gload_lds16(gB_ + 6144 + tid * 8, lB_ + 6144 + tid * 8);            \
  } while (0)

#define LOADF(da, db, t) do {                                           \
    const short* lA_ = lds + ((t) % 3) * RSTRIDE;                       \
    const short* lB_ = lA_ + 4096;                                      \
    _Pragma("unroll")                                                   \
    for (int mi = 0; mi < 4; ++mi) da[mi] = *(const short8*)&lA_[aoff[mi]]; \
    _Pragma("unroll")                                                   \
    for (int ni = 0; ni < 8; ++ni) db[ni] = *(const short8*)&lB_[boff[ni]]; \
  } while (0)

#define DOMFMA(sa, sb) do {                                             \
    __builtin_amdgcn_s_setprio(1);                                      \
    _Pragma("unroll")                                                   \
    for (int mi = 0; mi < 4; ++mi)                                      \
      _Pragma("unroll")                                                 \
      for (int ni = 0; ni < 8; ++ni)                                    \
        acc[mi][ni] = __builtin_amdgcn_mfma_f32_16x16x32_bf16(          \
            sa[mi], sb[ni], acc[mi][ni], 0, 0, 0);                      \
    __builtin_amdgcn_s_setprio(0);                                      \
  } while (0)

  // prologue: stage 3 tiles (18 loads); retire tile 0; publish; read frags
  STAGE(0); STAGE(1); STAGE(2);
  VMCNT(12);
  BARRIER;
  LOADF(fa, fb, 0);

  // Steady half-iter (tile kt current):
  //   VMCNT(6): outstanding [kt+1(6), kt+2(6)] -> retire kt+1
  //   LGKM0   : drain own ds_reads of slot kt%3 (issued last half-iter)
  //             BEFORE the barrier -> cross-wave safe vs STAGE below
  //   BARRIER : publish tile kt+1 (r6-proven publish-then-read)
  //   STAGE(kt+3): writes slot kt%3 (reads drained pre-barrier by ALL waves)
  //   LOADF(kt+1) overlaps DOMFMA(kt) (regs from last half-iter)
  for (int kt = 0; kt < 124; kt += 2) {
    VMCNT(6);
    LGKM0;
    BARRIER;
    STAGE(kt + 3);
    LOADF(ga, gb, kt + 1);
    DOMFMA(fa, fb);            // tile kt
    VMCNT(6);
    LGKM0;
    BARRIER;
    STAGE(kt + 4);
    LOADF(fa, fb, kt + 2);
    DOMFMA(ga, gb);            // tile kt+1
  }

  // tail: outstanding [125(6),126(6)]; fa holds tile 124 frags
  VMCNT(6);
  LGKM0;
  BARRIER;
  STAGE(127);
  LOADF(ga, gb, 125);
  DOMFMA(fa, fb);              // 124
  VMCNT(6);                    // retire 126
  LGKM0;
  BARRIER;
  LOADF(fa, fb, 126);
  DOMFMA(ga, gb);              // 125
  VMCNT(0);                    // retire 127
  LGKM0;
  BARRIER;
  LOADF(ga, gb, 127);
  DOMFMA(fa, fb);              // 126
  DOMFMA(ga, gb);              // 127

#undef STAGE
#undef LOADF
#undef DOMFMA
#undef SBAR
#undef VMCNT
#undef LGKM0
#undef BARRIER

  // epilogue: C/D layout col = lane&15, row = (lane>>4)*4 + reg (verified)
  #pragma unroll
  for (int ni = 0; ni < 8; ++ni) {
    const int col = nt * 256 + wn * 128 + ni * 16 + lr;
    const float bvf = load_sc(bv, (size_t)col, s_is_f32);
    #pragma unroll
    for (int mi = 0; mi < 4; ++mi) {
      const int rbase = mt * 128 + wm * 64 + mi * 16 + lk * 4;
      #pragma unroll
      for (int rr = 0; rr < 4; ++rr)
        C[(size_t)(rbase + rr) * N_DIM + col] = acc[mi][ni][rr] + bvf;
    }
  }
}

// ============ fallback: round-2-verified fully fused kernel ============
__global__ __launch_bounds__(256)
void gemm_fused(const float* __restrict__ x, const void* __restrict__ qv,
                const void* __restrict__ sv, const void* __restrict__ bv,
                float* __restrict__ C) {
  __shared__ __align__(16) short As[128 * 64];
  __shared__ __align__(16) short Bs[128 * 64];

  const bool q_is_i32 = sniff_q_is_i32(qv);
  const bool s_is_f32 = sniff_s_is_f32(sv);

  const int tid  = threadIdx.x;
  const int lane = tid & 63;
  const int wid  = tid >> 6;
  const int wm = wid >> 1, wn = wid & 1;
  const int lr = lane & 15, lk = lane >> 4;

  const int nwg = gridDim.x;
  const int cpx = nwg >> 3;
  const int bid = blockIdx.x;
  const int swz = (bid & 7) * cpx + (bid >> 3);
  const int per_g = 4 * 86;
  const int g = swz / per_g;
  const int r = swz - g * per_g;
  const int mt = (g << 2) + (r & 3);
  const int nt = r >> 2;

  const int row0 = mt * 128;
  const int col0 = nt * 128;

  floatx4 acc[4][4];
  #pragma unroll
  for (int i = 0; i < 4; ++i)
    #pragma unroll
    for (int j = 0; j < 4; ++j)
      acc[i][j] = (floatx4){0.f, 0.f, 0.f, 0.f};

  for (int kt = 0; kt < K_DIM / 64; ++kt) {
    const int k0 = kt * 64;
    #pragma unroll
    for (int i = 0; i < 4; ++i) {
      const int cid = i * 256 + tid;
      const int arow = cid >> 3, ac = (cid & 7) << 3;
      const float4* p = (const float4*)(x + (size_t)(row0 + arow) * K_DIM + k0 + ac);
      float4 a = p[0], b = p[1];
      short8 h;
      h[0]=f2bf(a.x); h[1]=f2bf(a.y); h[2]=f2bf(a.z); h[3]=f2bf(a.w);
      h[4]=f2bf(b.x); h[5]=f2bf(b.y); h[6]=f2bf(b.z); h[7]=f2bf(b.w);
      *(short8*)&As[arow * 64 + ac] = h;
    }
    #pragma unroll
    for (int i = 0; i < 2; ++i) {
      const int cid = i * 256 + tid;
      const int brow = cid >> 2, bc = (cid & 3) << 4;
      const float s = load_sc(sv, (size_t)(col0 + brow) * 64 + kt, s_is_f32);
      int codes[16];
      if (q_is_i32) {
        const int* qq = (const int*)qv + (size_t)(col0 + brow) * K_DIM + k0 + bc;
        #pragma unroll
        for (int j = 0; j < 4; ++j) {
          int4 t = ((const int4*)qq)[j];
          codes[j*4+0]=t.x; codes[j*4+1]=t.y; codes[j*4+2]=t.z; codes[j*4+3]=t.w;
        }
      } else {
        union { int4 v; int8_t c[16]; } u;
        u.v = *(const int4*)((const int8_t*)qv + (size_t)(col0 + brow) * K_DIM + k0 + bc);
        #pragma unroll
        for (int j = 0; j < 16; ++j) codes[j] = (int)u.c[j];
      }
      short8 h0, h1;
      #pragma unroll
      for (int j = 0; j < 8; ++j) h0[j] = f2bf((float)codes[j] * s);
      #pragma unroll
      for (int j = 0; j < 8; ++j) h1[j] = f2bf((float)codes[8 + j] * s);
      *(short8*)&Bs[brow * 64 + bc]     = h0;
      *(short8*)&Bs[brow * 64 + bc + 8] = h1;
    }
    __syncthreads();
    #pragma unroll
    for (int ks = 0; ks < 2; ++ks) {
      short8 a[4], b[4];
      #pragma unroll
      for (int mi = 0; mi < 4; ++mi)
        a[mi] = *(const short8*)&As[(wm * 64 + mi * 16 + lr) * 64 + ks * 32 + lk * 8];
      #pragma unroll
      for (int ni = 0; ni < 4; ++ni)
        b[ni] = *(const short8*)&Bs[(wn * 64 + ni * 16 + lr) * 64 + ks * 32 + lk * 8];
      #pragma unroll
      for (int mi = 0; mi < 4; ++mi)
        #pragma unroll
        for (int ni = 0; ni < 4; ++ni)
          acc[mi][ni] = __builtin_amdgcn_mfma_f32_16x16x32_bf16(
              a[mi], b[ni], acc[mi][ni], 0, 0, 0);
    }
    __syncthreads();
  }

  #pragma unroll
  for (int ni = 0; ni < 4; ++ni) {
    const int col = col0 + wn * 64 + ni * 16 + lr;
    const float bvf = load_sc(bv, (size_t)col, s_is_f32);
    #pragma unroll
    for (int mi = 0; mi < 4; ++mi) {
      const int rbase = row0 + wm * 64 + mi * 16 + lk * 4;
      #pragma unroll
      for (int rr = 0; rr < 4; ++rr)
        C[(size_t)(rbase + rr) * N_DIM + col] = acc[mi][ni][rr] + bvf;
    }
  }
}

extern "C" void kernel_launch(void* const* d_in, const int* in_sizes, int n_in,
                              void* d_out, int out_size, void* d_ws, size_t ws_size,
                              hipStream_t stream) {
  const float* x  = (const float*)d_in[0];
  const void*  q  = (const void*)d_in[1];
  const void*  sc = (const void*)d_in[2];
  const void*  bs = (const void*)d_in[3];
  float* y = (float*)d_out;
  (void)in_sizes; (void)n_in; (void)out_size;

  const size_t xh_bytes = (size_t)M_DIM * K_DIM * 2;   // 64 MiB
  const size_t wq_bytes = (size_t)N_DIM * K_DIM * 2;   // ~86 MiB

  if (ws_size >= xh_bytes + wq_bytes) {   // confirmed available (r3-r15)
    short* xh = (short*)d_ws;
    short* wq = (short*)((char*)d_ws + xh_bytes);
    prep_fused<<<NT_TILES * 256 + (M_DIM / 256) * 256, dim3(256), 0, stream>>>(
        x, q, sc, xh, wq);
    gemm4<<<MT_TILES * NT_TILES, dim3(256), 0, stream>>>(xh, wq, sc, bs, y);
  } else {
    gemm_fused<<<(M_DIM / 128) * (N_DIM / 128), dim3(256), 0, stream>>>(x, q, sc, bs, y);
  }
}

// Round 17
// 749.975 us; speedup vs baseline: 1.0647x; 1.0059x over previous
//
#include <hip/hip_runtime.h>
#include <hip/hip_fp16.h>
#include <stdint.h>

// PrunedInt4Linear: y = x @ dequant(q, scales)^T + bias
// Round 17: r16 (= r14, verified best: 748-754 us) + ANTI-PHASE STAGGER.
// Ledger: per tile-period ~2400 cyc, MFMA 1242 (52%) + LDS ~950 are still
// serialized -- the two co-resident blocks phase-lock (identical periodic
// code + LDS-contention re-sync). Odd blocks sleep ~1150 cyc (half period)
// after prologue stage issue, so opposite-parity co-resident pairs interleave
// LDS phases against the partner's MFMA phases. Pure delay; zero invariant
// changes.

#define M_DIM 8192
#define N_DIM 11008
#define K_DIM 4096
#define MT_TILES 64            // 8192 / 128  (M-tile 128)
#define NT_TILES 43            // 11008 / 256
#define K_TILES 128            // 4096 / 32
#define SLAB 8192              // shorts per 256-row, 32-k ws slab
#define RSTRIDE 12288          // shorts per LDS ring slot: A 4096 + B 8192

typedef short short8 __attribute__((ext_vector_type(8)));   // 8 bf16
typedef float floatx4 __attribute__((ext_vector_type(4)));

// f32 -> bf16, round-to-nearest-even
__device__ __forceinline__ unsigned short f2bf(float f) {
  union { float f; uint32_t u; } c; c.f = f;
  uint32_t u = c.u;
  return (unsigned short)((u + 0x7FFFu + ((u >> 16) & 1u)) >> 16);
}

__device__ __forceinline__ float load_sc(const void* p, size_t idx, bool is_f32) {
  if (is_f32) return ((const float*)p)[idx];
  return __half2float(((const __half*)p)[idx]);
}

// ---- dtype sniffs (verified rounds 2-16) ----
__device__ __forceinline__ bool sniff_q_is_i32(const void* qv) {
  const int* w = (const int*)qv;
  bool ok = true;
  #pragma unroll
  for (int j = 0; j < 16; ++j) {
    int v = w[j];
    ok = ok && (v == (int)(signed char)(v & 0xFF));
  }
  return ok;
}
__device__ __forceinline__ bool sniff_s_is_f32(const void* sv) {
  const float* f = (const float*)sv;
  bool ok = true;
  #pragma unroll
  for (int j = 0; j < 8; ++j) {
    float v = f[j];
    ok = ok && (v > 4e-4f) && (v < 6e-2f);
  }
  return ok;
}

// async global -> LDS, 16B per lane (dest = wave-uniform base + lane*16)
__device__ __forceinline__ void gload_lds16(const short* g, short* l) {
  __builtin_amdgcn_global_load_lds(
      (const __attribute__((address_space(1))) uint32_t*)g,
      (__attribute__((address_space(3))) uint32_t*)l, 16, 0, 0);
}

// ============ fused prep (r8/r12/r14-verified) ============
// xh: [mt32 256-row][kt 128][slab]; (r,k): r*32 + ((k/8) ^ ((r>>1)&3))*8 + k%8
// wq: [nt 43][kt 128][slab]; same within-slab swizzle
__global__ __launch_bounds__(256)
void prep_fused(const float* __restrict__ x, const void* __restrict__ qv,
                const void* __restrict__ sv,
                short* __restrict__ xh, short* __restrict__ wq) {
  const int tid = threadIdx.x;
  int b = blockIdx.x;

  if (b < NT_TILES * 256) {
    // ---- W dequant ----
    const bool q_is_i32 = sniff_q_is_i32(qv);
    const bool s_is_f32 = sniff_s_is_f32(sv);
    const int nt = b >> 8;
    const int rem = b & 255;
    const int kt = rem >> 1, half = rem & 1;
    const int r = half * 128 + (tid >> 1);
    const int s0 = (tid & 1) * 2;
    const int o = nt * 256 + r;
    const int k0 = kt * 32 + s0 * 8;

    const float s = load_sc(sv, (size_t)o * 64 + (kt >> 1), s_is_f32);

    int codes[16];
    if (q_is_i32) {
      const int* qq = (const int*)qv + (size_t)o * K_DIM + k0;
      #pragma unroll
      for (int j = 0; j < 4; ++j) {
        int4 t = ((const int4*)qq)[j];
        codes[j*4+0]=t.x; codes[j*4+1]=t.y; codes[j*4+2]=t.z; codes[j*4+3]=t.w;
      }
    } else {
      union { int4 v; int8_t c[16]; } u;
      u.v = *(const int4*)((const int8_t*)qv + (size_t)o * K_DIM + k0);
      #pragma unroll
      for (int j = 0; j < 16; ++j) codes[j] = (int)u.c[j];
    }

    short8 h0, h1;
    #pragma unroll
    for (int j = 0; j < 8; ++j) h0[j] = f2bf((float)codes[j] * s);
    #pragma unroll
    for (int j = 0; j < 8; ++j) h1[j] = f2bf((float)codes[8 + j] * s);

    const int w = (r >> 1) & 3;
    short* slab = wq + ((size_t)nt * K_TILES + kt) * SLAB;
    *(short8*)&slab[r * 32 + ((s0    ) ^ w) * 8] = h0;
    *(short8*)&slab[r * 32 + ((s0 + 1) ^ w) * 8] = h1;
  } else {
    // ---- x convert ----
    b -= NT_TILES * 256;
    const int mt = b >> 8;
    const int rem = b & 255;
    const int kt = rem >> 1, half = rem & 1;
    const int r = half * 128 + (tid >> 1);
    const int s0 = (tid & 1) * 2;
    const int k0 = kt * 32 + s0 * 8;

    const float4* p = (const float4*)(x + (size_t)(mt * 256 + r) * K_DIM + k0);
    float4 f0 = p[0], f1 = p[1], f2 = p[2], f3 = p[3];
    short8 h0, h1;
    h0[0]=f2bf(f0.x); h0[1]=f2bf(f0.y); h0[2]=f2bf(f0.z); h0[3]=f2bf(f0.w);
    h0[4]=f2bf(f1.x); h0[5]=f2bf(f1.y); h0[6]=f2bf(f1.z); h0[7]=f2bf(f1.w);
    h1[0]=f2bf(f2.x); h1[1]=f2bf(f2.y); h1[2]=f2bf(f2.z); h1[3]=f2bf(f2.w);
    h1[4]=f2bf(f3.x); h1[5]=f2bf(f3.y); h1[6]=f2bf(f3.z); h1[7]=f2bf(f3.w);

    const int w = (r >> 1) & 3;
    short* slab = xh + ((size_t)mt * K_TILES + kt) * SLAB;
    *(short8*)&slab[r * 32 + ((s0    ) ^ w) * 8] = h0;
    *(short8*)&slab[r * 32 + ((s0 + 1) ^ w) * 8] = h1;
  }
}

// ============ GEMM: 128x256 tile, BK=32, 4 waves, 2 blocks/CU ============
__global__ __launch_bounds__(256, 2)
void gemm4(const short* __restrict__ xh, const short* __restrict__ wq,
           const void* __restrict__ sv, const void* __restrict__ bv,
           float* __restrict__ C) {
  __shared__ __align__(16) short lds[3 * RSTRIDE];   // 72 KiB: 3-deep ring

  const bool s_is_f32 = sniff_s_is_f32(sv);

  const int tid  = threadIdx.x;
  const int lane = tid & 63;
  const int wid  = tid >> 6;                  // 4 waves
  const int wm = wid >> 1, wn = wid & 1;      // 2x2 -> 64x128 out per wave
  const int lr = lane & 15, lk = lane >> 4;

  // nt-major XCD dispatch: 2752 = 8 * 344, 344 = 43 * 8 (bijective)
  const int bid = blockIdx.x;
  const int xcd = bid & 7;
  const int seq = bid >> 3;                   // [0,344)
  const int nt  = seq >> 3;                   // [0,43)
  const int mt  = xcd * 8 + (seq & 7);        // [0,64) (128-row tiles)

  // A = 128-row half of the 256-row ws slab (contiguous; swizzle invariant)
  const short* Aslab = xh + (size_t)(mt >> 1) * (K_TILES * SLAB) + (mt & 1) * 4096;
  const short* Bslab = wq + (size_t)nt * (K_TILES * SLAB);

  // fragment LDS offsets (r4-verified swizzle, 0 conflicts)
  const int swz8 = (lk ^ ((lr >> 1) & 3)) << 3;
  int aoff[4], boff[8];
  #pragma unroll
  for (int mi = 0; mi < 4; ++mi) aoff[mi] = (wm * 64 + mi * 16 + lr) * 32 + swz8;
  #pragma unroll
  for (int ni = 0; ni < 8; ++ni) boff[ni] = (wn * 128 + ni * 16 + lr) * 32 + swz8;

  floatx4 acc[4][8];
  #pragma unroll
  for (int i = 0; i < 4; ++i)
    #pragma unroll
    for (int j = 0; j < 8; ++j)
      acc[i][j] = (floatx4){0.f, 0.f, 0.f, 0.f};

  short8 fa[4], fb[8], ga[4], gb[8];   // two named frag sets (rule #20)

#define SBAR __builtin_amdgcn_sched_barrier(0)
#define VMCNT(n) do { asm volatile("s_waitcnt vmcnt(" #n ")"); SBAR; } while (0)
#define LGKM0 do { asm volatile("s_waitcnt lgkmcnt(0)"); SBAR; } while (0)
#define BARRIER do { SBAR; __builtin_amdgcn_s_barrier(); SBAR; } while (0)

// stage = 6 loads: A half-slab 8 KB (2) + B slab 16 KB (4)
#define STAGE(t) do {                                                   \
    const int s_ = (t) % 3;                                             \
    const short* gA_ = Aslab + (size_t)(t) * SLAB;                      \
    const short* gB_ = Bslab + (size_t)(t) * SLAB;                      \
    short* lA_ = lds + s_ * RSTRIDE;                                    \
    short* lB_ = lA_ + 4096;                                            \
    gload_lds16(gA_ + tid * 8,        lA_ + tid * 8);                   \
    gload_lds16(gA_ + 2048 + tid * 8, lA_ + 2048 + tid * 8);            \
    gload_lds16(gB_ + tid * 8,        lB_ + tid * 8);                   \
    gload_lds16(gB_ + 2048 + tid * 8, lB_ + 2048 + tid * 8);            \
    gload_lds16(gB_ + 4096 + tid * 8, lB_ + 4096 + tid * 8);            \
    gload_lds16(gB_ + 6144 + tid * 8, lB_ + 6144 + tid * 8);            \
  } while (0)

#define LOADF(da, db, t) do {                                           \
    const short* lA_ = lds + ((t) % 3) * RSTRIDE;                       \
    const short* lB_ = lA_ + 4096;                                      \
    _Pragma("unroll")                                                   \
    for (int mi = 0; mi < 4; ++mi) da[mi] = *(const short8*)&lA_[aoff[mi]]; \
    _Pragma("unroll")                                                   \
    for (int ni = 0; ni < 8; ++ni) db[ni] = *(const short8*)&lB_[boff[ni]]; \
  } while (0)

#define DOMFMA(sa, sb) do {                                             \
    __builtin_amdgcn_s_setprio(1);                                      \
    _Pragma("unroll")                                                   \
    for (int mi = 0; mi < 4; ++mi)                                      \
      _Pragma("unroll")                                                 \
      for (int ni = 0; ni < 8; ++ni)                                    \
        acc[mi][ni] = __builtin_amdgcn_mfma_f32_16x16x32_bf16(          \
            sa[mi], sb[ni], acc[mi][ni], 0, 0, 0);                      \
    __builtin_amdgcn_s_setprio(0);                                      \
  } while (0)

  // prologue: stage 3 tiles (18 loads, DMA proceeds during any sleep)
  STAGE(0); STAGE(1); STAGE(2);

  // ANTI-PHASE STAGGER: odd blocks delay ~1152 cyc (half a tile-period) so
  // opposite-parity co-resident pairs interleave LDS phases vs MFMA phases.
  if (bid & 1) {
    asm volatile("s_sleep 9");   // ~576 cyc
    asm volatile("s_sleep 9");   // ~576 cyc more
  }

  VMCNT(12);
  BARRIER;
  LOADF(fa, fb, 0);

  // Steady half-iter (r14-proven):
  //   VMCNT(6): outstanding [kt+1(6), kt+2(6)] -> retire kt+1
  //   LGKM0   : drain own ds_reads of slot kt%3 BEFORE the barrier
  //   BARRIER : publish tile kt+1 (publish-then-read)
  //   STAGE(kt+3): writes slot kt%3 (reads drained pre-barrier by ALL waves)
  //   LOADF(kt+1) overlaps DOMFMA(kt)
  for (int kt = 0; kt < 124; kt += 2) {
    VMCNT(6);
    LGKM0;
    BARRIER;
    STAGE(kt + 3);
    LOADF(ga, gb, kt + 1);
    DOMFMA(fa, fb);            // tile kt
    VMCNT(6);
    LGKM0;
    BARRIER;
    STAGE(kt + 4);
    LOADF(fa, fb, kt + 2);
    DOMFMA(ga, gb);            // tile kt+1
  }

  // tail: outstanding [125(6),126(6)]; fa holds tile 124 frags
  VMCNT(6);
  LGKM0;
  BARRIER;
  STAGE(127);
  LOADF(ga, gb, 125);
  DOMFMA(fa, fb);              // 124
  VMCNT(6);                    // retire 126
  LGKM0;
  BARRIER;
  LOADF(fa, fb, 126);
  DOMFMA(ga, gb);              // 125
  VMCNT(0);                    // retire 127
  LGKM0;
  BARRIER;
  LOADF(ga, gb, 127);
  DOMFMA(fa, fb);              // 126
  DOMFMA(ga, gb);              // 127

#undef STAGE
#undef LOADF
#undef DOMFMA
#undef SBAR
#undef VMCNT
#undef LGKM0
#undef BARRIER

  // epilogue: C/D layout col = lane&15, row = (lane>>4)*4 + reg (verified)
  #pragma unroll
  for (int ni = 0; ni < 8; ++ni) {
    const int col = nt * 256 + wn * 128 + ni * 16 + lr;
    const float bvf = load_sc(bv, (size_t)col, s_is_f32);
    #pragma unroll
    for (int mi = 0; mi < 4; ++mi) {
      const int rbase = mt * 128 + wm * 64 + mi * 16 + lk * 4;
      #pragma unroll
      for (int rr = 0; rr < 4; ++rr)
        C[(size_t)(rbase + rr) * N_DIM + col] = acc[mi][ni][rr] + bvf;
    }
  }
}

// ============ fallback: round-2-verified fully fused kernel ============
__global__ __launch_bounds__(256)
void gemm_fused(const float* __restrict__ x, const void* __restrict__ qv,
                const void* __restrict__ sv, const void* __restrict__ bv,
                float* __restrict__ C) {
  __shared__ __align__(16) short As[128 * 64];
  __shared__ __align__(16) short Bs[128 * 64];

  const bool q_is_i32 = sniff_q_is_i32(qv);
  const bool s_is_f32 = sniff_s_is_f32(sv);

  const int tid  = threadIdx.x;
  const int lane = tid & 63;
  const int wid  = tid >> 6;
  const int wm = wid >> 1, wn = wid & 1;
  const int lr = lane & 15, lk = lane >> 4;

  const int nwg = gridDim.x;
  const int cpx = nwg >> 3;
  const int bid = blockIdx.x;
  const int swz = (bid & 7) * cpx + (bid >> 3);
  const int per_g = 4 * 86;
  const int g = swz / per_g;
  const int r = swz - g * per_g;
  const int mt = (g << 2) + (r & 3);
  const int nt = r >> 2;

  const int row0 = mt * 128;
  const int col0 = nt * 128;

  floatx4 acc[4][4];
  #pragma unroll
  for (int i = 0; i < 4; ++i)
    #pragma unroll
    for (int j = 0; j < 4; ++j)
      acc[i][j] = (floatx4){0.f, 0.f, 0.f, 0.f};

  for (int kt = 0; kt < K_DIM / 64; ++kt) {
    const int k0 = kt * 64;
    #pragma unroll
    for (int i = 0; i < 4; ++i) {
      const int cid = i * 256 + tid;
      const int arow = cid >> 3, ac = (cid & 7) << 3;
      const float4* p = (const float4*)(x + (size_t)(row0 + arow) * K_DIM + k0 + ac);
      float4 a = p[0], b = p[1];
      short8 h;
      h[0]=f2bf(a.x); h[1]=f2bf(a.y); h[2]=f2bf(a.z); h[3]=f2bf(a.w);
      h[4]=f2bf(b.x); h[5]=f2bf(b.y); h[6]=f2bf(b.z); h[7]=f2bf(b.w);
      *(short8*)&As[arow * 64 + ac] = h;
    }
    #pragma unroll
    for (int i = 0; i < 2; ++i) {
      const int cid = i * 256 + tid;
      const int brow = cid >> 2, bc = (cid & 3) << 4;
      const float s = load_sc(sv, (size_t)(col0 + brow) * 64 + kt, s_is_f32);
      int codes[16];
      if (q_is_i32) {
        const int* qq = (const int*)qv + (size_t)(col0 + brow) * K_DIM + k0 + bc;
        #pragma unroll
        for (int j = 0; j < 4; ++j) {
          int4 t = ((const int4*)qq)[j];
          codes[j*4+0]=t.x; codes[j*4+1]=t.y; codes[j*4+2]=t.z; codes[j*4+3]=t.w;
        }
      } else {
        union { int4 v; int8_t c[16]; } u;
        u.v = *(const int4*)((const int8_t*)qv + (size_t)(col0 + brow) * K_DIM + k0 + bc);
        #pragma unroll
        for (int j = 0; j < 16; ++j) codes[j] = (int)u.c[j];
      }
      short8 h0, h1;
      #pragma unroll
      for (int j = 0; j < 8; ++j) h0[j] = f2bf((float)codes[j] * s);
      #pragma unroll
      for (int j = 0; j < 8; ++j) h1[j] = f2bf((float)codes[8 + j] * s);
      *(short8*)&Bs[brow * 64 + bc]     = h0;
      *(short8*)&Bs[brow * 64 + bc + 8] = h1;
    }
    __syncthreads();
    #pragma unroll
    for (int ks = 0; ks < 2; ++ks) {
      short8 a[4], b[4];
      #pragma unroll
      for (int mi = 0; mi < 4; ++mi)
        a[mi] = *(const short8*)&As[(wm * 64 + mi * 16 + lr) * 64 + ks * 32 + lk * 8];
      #pragma unroll
      for (int ni = 0; ni < 4; ++ni)
        b[ni] = *(const short8*)&Bs[(wn * 64 + ni * 16 + lr) * 64 + ks * 32 + lk * 8];
      #pragma unroll
      for (int mi = 0; mi < 4; ++mi)
        #pragma unroll
        for (int ni = 0; ni < 4; ++ni)
          acc[mi][ni] = __builtin_amdgcn_mfma_f32_16x16x32_bf16(
              a[mi], b[ni], acc[mi][ni], 0, 0, 0);
    }
    __syncthreads();
  }

  #pragma unroll
  for (int ni = 0; ni < 4; ++ni) {
    const int col = col0 + wn * 64 + ni * 16 + lr;
    const float bvf = load_sc(bv, (size_t)col, s_is_f32);
    #pragma unroll
    for (int mi = 0; mi < 4; ++mi) {
      const int rbase = row0 + wm * 64 + mi * 16 + lk * 4;
      #pragma unroll
      for (int rr = 0; rr < 4; ++rr)
        C[(size_t)(rbase + rr) * N_DIM + col] = acc[mi][ni][rr] + bvf;
    }
  }
}

extern "C" void kernel_launch(void* const* d_in, const int* in_sizes, int n_in,
                              void* d_out, int out_size, void* d_ws, size_t ws_size,
                              hipStream_t stream) {
  const float* x  = (const float*)d_in[0];
  const void*  q  = (const void*)d_in[1];
  const void*  sc = (const void*)d_in[2];
  const void*  bs = (const void*)d_in[3];
  float* y = (float*)d_out;
  (void)in_sizes; (void)n_in; (void)out_size;

  const size_t xh_bytes = (size_t)M_DIM * K_DIM * 2;   // 64 MiB
  const size_t wq_bytes = (size_t)N_DIM * K_DIM * 2;   // ~86 MiB

  if (ws_size >= xh_bytes + wq_bytes) {   // confirmed available (r3-r16)
    short* xh = (short*)d_ws;
    short* wq = (short*)((char*)d_ws + xh_bytes);
    prep_fused<<<NT_TILES * 256 + (M_DIM / 256) * 256, dim3(256), 0, stream>>>(
        x, q, sc, xh, wq);
    gemm4<<<MT_TILES * NT_TILES, dim3(256), 0, stream>>>(xh, wq, sc, bs, y);
  } else {
    gemm_fused<<<(M_DIM / 128) * (N_DIM / 128), dim3(256), 0, stream>>>(x, q, sc, bs, y);
  }
}